// Round 3
// baseline (156.209 us; speedup 1.0000x reference)
//
#include <hip/hip_runtime.h>

// LaplaceCostNet — MI355X (gfx950)
// Round-3: inputs ARE fp32 (round-1 NaN = fp32-read-as-bf16; round-2 detector
// proved fp32 branch), output IS fp32 (round-2's 56.34 = bf16-packed output
// scrambled under the harness's float32 read). fp32 in, fp32 out; bf16 only
// internally for MFMA weights/activations.
//
// Workspace layout (bytes):
//   [4096   .. 135168)    WT bf16: WT[l][n][k] = Wh[l][k][n]
//   [262144 .. +1MB)      C    fp32
//   [+1MB   .. +2MB)      Cs   fp32
//   [+2MB   .. +3MB)      VA   fp32
//   [+3MB   .. +4MB)      VB   fp32

typedef unsigned short ushort_t;
typedef short short8 __attribute__((ext_vector_type(8)));
typedef float floatx4 __attribute__((ext_vector_type(4)));

#define HH 512
#define WW 512
#define NPIX (HH*WW)
#define AS 136  // LDS act/weight row stride in bf16 elems (272 B, 16B-multiple)

__device__ inline ushort_t f2bf(float f) {
    union { float f; unsigned int i; } v; v.f = f;
    unsigned int u = v.i;
    unsigned int r = u + 0x7FFFu + ((u >> 16) & 1u);  // RNE
    return (ushort_t)(r >> 16);
}
__device__ inline float bf2f(ushort_t u) {
    union { unsigned int i; float f; } v; v.i = ((unsigned int)u) << 16; return v.f;
}

// ---------------- prep: transpose+downcast weights ----------------
__global__ void prep_kernel(const float* __restrict__ Wh,
                            ushort_t* __restrict__ WT) {
    int idx = blockIdx.x * 256 + threadIdx.x;       // 0..65535
    int l = idx >> 14, rem = idx & 16383;
    int n = rem >> 7, k = rem & 127;
    WT[idx] = f2bf(Wh[l * 16384 + k * 128 + n]);    // WT[l][n][k] = Wh[l][k][n]
}

// ---------------- MLP: encoding + 4x (128x128 GEMM, relu) + output dot ----------------
// Per block: 128 points. Weights = MFMA A operand (m = out-neuron),
// activations = B operand (n = point). D layout (m89): row=quad*4+reg, col=lane&15.
__global__ __launch_bounds__(256, 2) void mlp_kernel(const float* __restrict__ x,
                                                     const ushort_t* __restrict__ WT,
                                                     const float* __restrict__ benc,
                                                     const float* __restrict__ wout,
                                                     float* __restrict__ C_ws,
                                                     float* __restrict__ outbuf) {
    __shared__ __align__(16) ushort_t act[128 * AS];
    __shared__ __align__(16) ushort_t wbuf[128 * AS];
    const int tid = threadIdx.x;
    const int p0 = blockIdx.x * 128;

    // --- Fourier encoding: enc = [cos(vp), sin(vp)], vp = 2pi * (xq @ B^T) ---
    {
        int p = tid >> 1, half = tid & 1;           // half 0: cos (n 0..63), half 1: sin (n 64..127)
        float2 xv = ((const float2*)x)[p0 + p];
        float xq0 = 0.5f + 0.5f * xv.x, xq1 = 0.5f + 0.5f * xv.y;
        ushort_t* dst = &act[p * AS + half * 64];
        #pragma unroll 4
        for (int f = 0; f < 64; f += 2) {
            float vp0 = 6.28318530718f * (xq0 * benc[2 * f]     + xq1 * benc[2 * f + 1]);
            float vp1 = 6.28318530718f * (xq0 * benc[2 * f + 2] + xq1 * benc[2 * f + 3]);
            float s0, c0, s1, c1;
            __sincosf(vp0, &s0, &c0);
            __sincosf(vp1, &s1, &c1);
            float v0 = half ? s0 : c0;
            float v1 = half ? s1 : c1;
            unsigned int pk = (unsigned int)f2bf(v0) | ((unsigned int)f2bf(v1) << 16);
            *(unsigned int*)&dst[f] = pk;
        }
    }

    const int lane = tid & 63, wave = tid >> 6;
    const int quad = lane >> 4, l16 = lane & 15;
    const int ntb = (wave >> 1) * 64;   // this wave's out-neuron range
    const int ptb = (wave & 1) * 64;    // this wave's point range

    #pragma unroll 1
    for (int l = 0; l < 4; ++l) {
        // stage layer weights WT[l] (32 KB) -> wbuf
        {
            const uint4* src = (const uint4*)(WT + l * 16384);
            #pragma unroll
            for (int c = 0; c < 8; ++c) {
                int chunk = tid + c * 256;             // 0..2047 16B chunks
                int row = chunk >> 4, off = (chunk & 15) * 8;
                *(uint4*)&wbuf[row * AS + off] = src[chunk];
            }
        }
        __syncthreads();   // act inputs + wbuf visible

        floatx4 acc[4][4];
        #pragma unroll
        for (int i = 0; i < 4; ++i)
            #pragma unroll
            for (int j = 0; j < 4; ++j)
                acc[i][j] = floatx4{0.0f, 0.0f, 0.0f, 0.0f};

        #pragma unroll
        for (int ks = 0; ks < 4; ++ks) {
            int koff = ks * 32 + quad * 8;
            short8 af[4], bv[4];
            #pragma unroll
            for (int i = 0; i < 4; ++i)
                af[i] = *(const short8*)&wbuf[(ntb + i * 16 + l16) * AS + koff];
            #pragma unroll
            for (int j = 0; j < 4; ++j)
                bv[j] = *(const short8*)&act[(ptb + j * 16 + l16) * AS + koff];
            #pragma unroll
            for (int i = 0; i < 4; ++i)
                #pragma unroll
                for (int j = 0; j < 4; ++j)
                    acc[i][j] = __builtin_amdgcn_mfma_f32_16x16x32_bf16(af[i], bv[j], acc[i][j], 0, 0, 0);
        }
        __syncthreads();   // all reads done before act overwrite

        // write-back: lane holds point p = ptb+j*16+l16 (col), neurons n0..n0+3 (rows)
        #pragma unroll
        for (int i = 0; i < 4; ++i) {
            #pragma unroll
            for (int j = 0; j < 4; ++j) {
                int p = ptb + j * 16 + l16;
                int n0 = ntb + i * 16 + quad * 4;
                float r0 = fmaxf(acc[i][j][0], 0.0f);
                float r1 = fmaxf(acc[i][j][1], 0.0f);
                float r2 = fmaxf(acc[i][j][2], 0.0f);
                float r3 = fmaxf(acc[i][j][3], 0.0f);
                uint2 pk;
                pk.x = (unsigned int)f2bf(r0) | ((unsigned int)f2bf(r1) << 16);
                pk.y = (unsigned int)f2bf(r2) | ((unsigned int)f2bf(r3) << 16);
                *(uint2*)&act[p * AS + n0] = pk;
            }
        }
        __syncthreads();
    }

    // final linear: C[p] = h . wout (fp32, no relu)
    if (tid < 128) {
        int p = tid;
        float sum = 0.0f;
        #pragma unroll
        for (int g = 0; g < 16; ++g) {
            short8 v = *(const short8*)&act[p * AS + g * 8];
            #pragma unroll
            for (int e = 0; e < 8; ++e)
                sum += bf2f((ushort_t)v[e]) * wout[g * 8 + e];
        }
        C_ws[p0 + p] = sum;
        outbuf[NPIX + p0 + p] = sum;   // output 1: C (fp32)
    }
}

// ---------------- cost: Cs = relu(C) + box5(obj)*free ; V0 ----------------
__global__ void cost_kernel(const int* __restrict__ bt,
                            const float* __restrict__ bc,
                            const float* __restrict__ C_ws,
                            float* __restrict__ Cs,
                            float* __restrict__ V0) {
    __shared__ float obj[20 * 20];
    int tid = threadIdx.x;
    int bx = (blockIdx.x & 31) * 16, by = (blockIdx.x >> 5) * 16;
    for (int c = tid; c < 400; c += 256) {
        int li = c / 20, lj = c - li * 20;
        int gi = by + li - 2, gj = bx + lj - 2;
        float v = 0.0f;                               // zero pad (conv SAME)
        if (gi >= 0 && gi < HH && gj >= 0 && gj < WW) {
            int g = gi * WW + gj;
            float b = bc[g];
            if (bt[g] == 1 && b > 0.0f) v = b;
        }
        obj[c] = v;
    }
    __syncthreads();
    int ty = tid >> 4, tx = tid & 15;
    float s = 0.0f;
    #pragma unroll
    for (int di = 0; di < 5; ++di)
        #pragma unroll
        for (int dj = 0; dj < 5; ++dj)
            s += obj[(ty + di) * 20 + tx + dj];
    int g = (by + ty) * WW + (bx + tx);
    float cpos = fmaxf(C_ws[g], 0.0f);
    bool freec = (bt[g] == 0);
    Cs[g] = cpos + (freec ? s * 0.04f : 0.0f);
    V0[g] = freec ? 100.0f : bc[g];
}

// ---------------- one Jacobi pass (edge-padded 8-neighbor average) ----------------
__global__ void solve_kernel(const float* __restrict__ Vin,
                             float* __restrict__ Vout,
                             const float* __restrict__ Cs,
                             const int* __restrict__ bt,
                             const float* __restrict__ bc) {
    int idx = blockIdx.x * 256 + threadIdx.x;
    int i = idx >> 9, j = idx & 511;
    float r;
    if (bt[idx] != 0) {
        r = bc[idx];
    } else {
        int im = i > 0 ? i - 1 : 0, ip = i < 511 ? i + 1 : 511;
        int jm = j > 0 ? j - 1 : 0, jp = j < 511 ? j + 1 : 511;
        float s = Vin[im * 512 + jm] + Vin[im * 512 + j] + Vin[im * 512 + jp]
                + Vin[i  * 512 + jm]                     + Vin[i  * 512 + jp]
                + Vin[ip * 512 + jm] + Vin[ip * 512 + j] + Vin[ip * 512 + jp];
        r = s * 0.125f + Cs[idx];
    }
    Vout[idx] = r;
}

// ---------------- bilinear grid sample (align_corners, border clamp) ----------------
__global__ void sample_kernel(const float* __restrict__ x,
                              const float* __restrict__ V,
                              float* __restrict__ out) {
    int idx = blockIdx.x * 256 + threadIdx.x;
    float2 g2 = ((const float2*)x)[idx];
    float ix = (g2.x + 1.0f) * 0.5f * 511.0f;
    float iy = (g2.y + 1.0f) * 0.5f * 511.0f;
    ix = fminf(fmaxf(ix, 0.0f), 511.0f);
    iy = fminf(fmaxf(iy, 0.0f), 511.0f);
    int x0 = (int)floorf(ix), y0 = (int)floorf(iy);
    int x1 = min(x0 + 1, 511), y1 = min(y0 + 1, 511);
    float wx = ix - (float)x0, wy = iy - (float)y0;
    float v00 = V[y0 * 512 + x0], v01 = V[y0 * 512 + x1];
    float v10 = V[y1 * 512 + x0], v11 = V[y1 * 512 + x1];
    float v = v00 * (1.0f - wx) * (1.0f - wy) + v01 * wx * (1.0f - wy)
            + v10 * (1.0f - wx) * wy          + v11 * wx * wy;
    out[idx] = v;   // output 0 (fp32)
}

extern "C" void kernel_launch(void* const* d_in, const int* in_sizes, int n_in,
                              void* d_out, int out_size, void* d_ws, size_t ws_size,
                              hipStream_t stream) {
    const float* x    = (const float*)d_in[0];
    const int*   bt   = (const int*)d_in[1];
    const float* bc   = (const float*)d_in[2];
    const float* benc = (const float*)d_in[3];
    const float* Wh   = (const float*)d_in[4];
    const float* wout = (const float*)d_in[5];

    char* ws = (char*)d_ws;
    ushort_t* WT   = (ushort_t*)(ws + 4096);
    float*    C_ws = (float*)(ws + 262144);
    float*    Cs   = (float*)(ws + 262144 + 1 * (1 << 20));
    float*    VA   = (float*)(ws + 262144 + 2 * (1 << 20));
    float*    VB   = (float*)(ws + 262144 + 3 * (1 << 20));
    float*    outp = (float*)d_out;

    prep_kernel<<<256, 256, 0, stream>>>(Wh, WT);
    mlp_kernel<<<2048, 256, 0, stream>>>(x, WT, benc, wout, C_ws, outp);
    cost_kernel<<<1024, 256, 0, stream>>>(bt, bc, C_ws, Cs, VA);
    solve_kernel<<<1024, 256, 0, stream>>>(VA, VB, Cs, bt, bc);
    solve_kernel<<<1024, 256, 0, stream>>>(VB, VA, Cs, bt, bc);
    solve_kernel<<<1024, 256, 0, stream>>>(VA, VB, Cs, bt, bc);
    solve_kernel<<<1024, 256, 0, stream>>>(VB, VA, Cs, bt, bc);
    solve_kernel<<<1024, 256, 0, stream>>>(VA, VB, Cs, bt, bc);
    sample_kernel<<<1024, 256, 0, stream>>>(x, VB, outp);
}

// Round 4
// 144.706 us; speedup vs baseline: 1.0795x; 1.0795x over previous
//
#include <hip/hip_runtime.h>

// LaplaceCostNet — MI355X (gfx950), round 4.
// R3 passed @156 µs: mlp 72.8 µs + ~83 µs of 8 small launches.
// R4: (a) fuse cost+5×Jacobi into one tiled LDS kernel (9->4 dispatches);
//     (b) mlp: XOR-swizzled LDS (kill 6.8M bank-conflict cycles),
//         half-sincos encoding, global_load_lds weight staging (pre-swizzled WT),
//         parallel final dot.
//
// Workspace (bytes):
//   [4096   .. 135168)  WT bf16, PRE-SWIZZLED: chunk layout matches LDS DMA order
//   [262144 .. +1MB)    C    fp32
//   [262144+3MB .. +4MB) Vfin fp32

typedef unsigned short ushort_t;
typedef short short8 __attribute__((ext_vector_type(8)));
typedef float floatx4 __attribute__((ext_vector_type(4)));

#define HH 512
#define WW 512
#define NPIX (HH*WW)

// swizzled element address within a 128-elem row: chunk (16B/8elem) XOR row&15
#define SW(p, f) (((p) << 7) + (((((f) >> 3) ^ ((p) & 15))) << 3) + ((f) & 7))

__device__ inline ushort_t f2bf(float f) {
    union { float f; unsigned int i; } v; v.f = f;
    unsigned int u = v.i;
    unsigned int r = u + 0x7FFFu + ((u >> 16) & 1u);  // RNE
    return (ushort_t)(r >> 16);
}
__device__ inline float bf2f(ushort_t u) {
    union { unsigned int i; float f; } v; v.i = ((unsigned int)u) << 16; return v.f;
}

__device__ inline void async_copy16(void* lds, const void* g) {
    __builtin_amdgcn_global_load_lds(
        (const __attribute__((address_space(1))) unsigned int*)g,
        (__attribute__((address_space(3))) unsigned int*)lds, 16, 0, 0);
}

// ---------------- prep: transpose+downcast+PRE-SWIZZLE weights ----------------
// WT physical chunk (l, n, pc) holds logical chunk c = pc ^ (n&15) of row n,
// i.e. elems k = c*8 .. c*8+7 of Wh[l][:,n] — so a linear 16B LDS DMA recreates
// the swizzled layout the MFMA readers expect.
__global__ void prep_kernel(const float* __restrict__ Wh,
                            uint4* __restrict__ WT) {
    int g = blockIdx.x * 256 + threadIdx.x;         // 0..8191 chunks
    int pc = g & 15, n = (g >> 4) & 127, l = g >> 11;
    int c = pc ^ (n & 15);
    int k0 = c << 3;
    const float* src = Wh + l * 16384 + n;
    unsigned int w[4];
    #pragma unroll
    for (int j = 0; j < 4; ++j) {
        ushort_t a = f2bf(src[(k0 + 2 * j)     * 128]);
        ushort_t b = f2bf(src[(k0 + 2 * j + 1) * 128]);
        w[j] = (unsigned int)a | ((unsigned int)b << 16);
    }
    WT[g] = uint4{w[0], w[1], w[2], w[3]};
}

// ---------------- MLP ----------------
__global__ __launch_bounds__(256, 2) void mlp_kernel(const float* __restrict__ x,
                                                     const ushort_t* __restrict__ WT,
                                                     const float* __restrict__ benc,
                                                     const float* __restrict__ wout,
                                                     float* __restrict__ C_ws,
                                                     float* __restrict__ outbuf) {
    __shared__ __align__(16) ushort_t act[128 * 128];   // 32 KB, swizzled rows
    __shared__ __align__(16) ushort_t wbuf[128 * 128];  // 32 KB, swizzled rows
    const int tid = threadIdx.x;
    const int p0 = blockIdx.x * 128;
    const int lane = tid & 63, wave = tid >> 6;

    // kick off async staging of layer-0 weights (pre-swizzled, linear DMA)
    {
        const char* src = (const char*)WT;  // layer 0
        int base = wave * 512;              // chunk index base for this wave
        #pragma unroll
        for (int c2 = 0; c2 < 8; ++c2) {
            int cb = base + c2 * 64;
            async_copy16(&wbuf[cb * 8], src + (cb + lane) * 16);
        }
    }

    // --- Fourier encoding: thread (p, h) covers f in [h*32, h*32+32), uses BOTH sin&cos ---
    {
        int p = tid >> 1, h = tid & 1;
        float2 xv = ((const float2*)x)[p0 + p];
        float xq0 = 0.5f + 0.5f * xv.x, xq1 = 0.5f + 0.5f * xv.y;
        const float4* b4 = (const float4*)benc;
        #pragma unroll 4
        for (int f2 = 0; f2 < 32; f2 += 2) {
            int f = h * 32 + f2;
            float4 b = b4[f >> 1];   // benc[2f..2f+3]
            float vp0 = 6.28318530718f * (xq0 * b.x + xq1 * b.y);
            float vp1 = 6.28318530718f * (xq0 * b.z + xq1 * b.w);
            float s0, c0, s1, c1;
            __sincosf(vp0, &s0, &c0);
            __sincosf(vp1, &s1, &c1);
            unsigned int pc = (unsigned int)f2bf(c0) | ((unsigned int)f2bf(c1) << 16);
            unsigned int ps = (unsigned int)f2bf(s0) | ((unsigned int)f2bf(s1) << 16);
            *(unsigned int*)&act[SW(p, f)]      = pc;   // cos -> n = f
            *(unsigned int*)&act[SW(p, f + 64)] = ps;   // sin -> n = f+64
        }
    }

    const int quad = lane >> 4, l16 = lane & 15;
    const int ntb = (wave >> 1) * 64;   // out-neuron range
    const int ptb = (wave & 1) * 64;    // point range

    #pragma unroll 1
    for (int l = 0; l < 4; ++l) {
        __syncthreads();   // act ready (enc or writeback), wbuf(l) DMA drained

        floatx4 acc[4][4];
        #pragma unroll
        for (int i = 0; i < 4; ++i)
            #pragma unroll
            for (int j = 0; j < 4; ++j)
                acc[i][j] = floatx4{0.0f, 0.0f, 0.0f, 0.0f};

        #pragma unroll
        for (int ks = 0; ks < 4; ++ks) {
            int cs = (ks * 4 + quad);         // logical chunk of this quad's k-slice
            short8 af[4], bv[4];
            #pragma unroll
            for (int i = 0; i < 4; ++i) {
                int r = ntb + i * 16 + l16;
                af[i] = *(const short8*)&wbuf[(r << 7) + ((cs ^ l16) << 3)];
            }
            #pragma unroll
            for (int j = 0; j < 4; ++j) {
                int p = ptb + j * 16 + l16;
                bv[j] = *(const short8*)&act[(p << 7) + ((cs ^ l16) << 3)];
            }
            #pragma unroll
            for (int i = 0; i < 4; ++i)
                #pragma unroll
                for (int j = 0; j < 4; ++j)
                    acc[i][j] = __builtin_amdgcn_mfma_f32_16x16x32_bf16(af[i], bv[j], acc[i][j], 0, 0, 0);
        }
        __syncthreads();   // all wbuf/act reads done

        if (l < 3) {       // async stage next layer while we write activations back
            const char* src = (const char*)WT + (l + 1) * 32768;
            int base = wave * 512;
            #pragma unroll
            for (int c2 = 0; c2 < 8; ++c2) {
                int cb = base + c2 * 64;
                async_copy16(&wbuf[cb * 8], src + (cb + lane) * 16);
            }
        }

        // writeback relu(acc) into act (swizzled): lane -> point p, neurons n0..n0+3
        #pragma unroll
        for (int i = 0; i < 4; ++i) {
            #pragma unroll
            for (int j = 0; j < 4; ++j) {
                int p = ptb + j * 16 + l16;
                int n0 = ntb + i * 16 + quad * 4;
                float r0 = fmaxf(acc[i][j][0], 0.0f);
                float r1 = fmaxf(acc[i][j][1], 0.0f);
                float r2 = fmaxf(acc[i][j][2], 0.0f);
                float r3 = fmaxf(acc[i][j][3], 0.0f);
                uint2 pk;
                pk.x = (unsigned int)f2bf(r0) | ((unsigned int)f2bf(r1) << 16);
                pk.y = (unsigned int)f2bf(r2) | ((unsigned int)f2bf(r3) << 16);
                *(uint2*)&act[SW(p, n0)] = pk;
            }
        }
    }
    __syncthreads();

    // final linear: two threads per point, 64 MACs each + shuffle combine
    {
        int p = tid >> 1, h = tid & 1;
        const float4* wo4 = (const float4*)wout;
        float sum = 0.0f;
        #pragma unroll
        for (int g = 0; g < 8; ++g) {
            int ch = h * 8 + g;
            short8 v = *(const short8*)&act[(p << 7) + ((ch ^ (p & 15)) << 3)];
            float4 wa = wo4[ch * 2], wb = wo4[ch * 2 + 1];
            sum += bf2f((ushort_t)v[0]) * wa.x + bf2f((ushort_t)v[1]) * wa.y
                 + bf2f((ushort_t)v[2]) * wa.z + bf2f((ushort_t)v[3]) * wa.w
                 + bf2f((ushort_t)v[4]) * wb.x + bf2f((ushort_t)v[5]) * wb.y
                 + bf2f((ushort_t)v[6]) * wb.z + bf2f((ushort_t)v[7]) * wb.w;
        }
        float other = __shfl_xor(sum, 1);
        if (h == 0) {
            float tot = sum + other;
            C_ws[p0 + p] = tot;
            outbuf[NPIX + p0 + p] = tot;   // output 1: C
        }
    }
}

// ---------------- fused: cost (box5 + Cs + V0) + 5 Jacobi passes ----------------
// 32x32 output tiles, halo 7. LDS stride 48.
#define TS 48
__global__ __launch_bounds__(256) void fused_solve_kernel(const int* __restrict__ bt,
                                                          const float* __restrict__ bc,
                                                          const float* __restrict__ C_ws,
                                                          float* __restrict__ Vfin) {
    __shared__ float Va[46 * TS];   // obj, then ping-pong
    __shared__ float Vb[46 * TS];   // V0,  then ping-pong
    __shared__ float Wp[46 * TS];   // pin-encoded cost: free -> Cs>=0, pinned -> -(bc+1)
    const int tid = threadIdx.x;
    const int tx0 = (blockIdx.x & 15) * 32, ty0 = (blockIdx.x >> 4) * 32;
    const int gx0 = tx0 - 7, gy0 = ty0 - 7;

    // Phase A: obj over full 46x46 region (zero outside grid / non-obstacle)
    for (int c = tid; c < 46 * 46; c += 256) {
        int li = c / 46, lj = c - li * 46;
        int gi = gy0 + li, gj = gx0 + lj;
        float v = 0.0f;
        if (gi >= 0 && gi < HH && gj >= 0 && gj < WW) {
            int g = gi * WW + gj;
            float b = bc[g];
            if (bt[g] == 1 && b > 0.0f) v = b;
        }
        Va[li * TS + lj] = v;
    }
    __syncthreads();

    // Phase B: W and V0 over radius-5 region [2,44)
    for (int c = tid; c < 42 * 42; c += 256) {
        int li = 2 + c / 42, lj = 2 + c - (c / 42) * 42;
        int gi = gy0 + li, gj = gx0 + lj;
        float w = -1.0f, v0 = 0.0f;
        if (gi >= 0 && gi < HH && gj >= 0 && gj < WW) {
            int g = gi * WW + gj;
            if (bt[g] == 0) {
                float s = 0.0f;
                #pragma unroll
                for (int di = 0; di < 5; ++di)
                    #pragma unroll
                    for (int dj = 0; dj < 5; ++dj)
                        s += Va[(li + di - 2) * TS + lj + dj - 2];
                w = fmaxf(C_ws[g], 0.0f) + s * 0.04f;
                v0 = 100.0f;
            } else {
                float b = bc[g];
                w = -b - 1.0f;
                v0 = b;
            }
        }
        Wp[li * TS + lj] = w;
        Vb[li * TS + lj] = v0;
    }
    __syncthreads();

    // Phase C: 5 Jacobi passes over fixed region [2,44) (outer rings go stale harmlessly)
    float* src = Vb;
    float* dst = Va;
    #pragma unroll 1
    for (int t = 0; t < 5; ++t) {
        for (int c = tid; c < 42 * 42; c += 256) {
            int li = 2 + c / 42, lj = 2 + c - (c / 42) * 42;
            int gi = gy0 + li, gj = gx0 + lj;
            if (gi < 0 || gi >= HH || gj < 0 || gj >= WW) continue;
            float w = Wp[li * TS + lj];
            float v;
            if (w < 0.0f) {
                v = -w - 1.0f;
            } else {
                int um = (gi > 0)      ? li - 1 : li;
                int dp = (gi < HH - 1) ? li + 1 : li;
                int lm = (gj > 0)      ? lj - 1 : lj;
                int rp = (gj < WW - 1) ? lj + 1 : lj;
                float s = src[um * TS + lm] + src[um * TS + lj] + src[um * TS + rp]
                        + src[li * TS + lm]                     + src[li * TS + rp]
                        + src[dp * TS + lm] + src[dp * TS + lj] + src[dp * TS + rp];
                v = s * 0.125f + w;
            }
            dst[li * TS + lj] = v;
        }
        __syncthreads();
        float* tmp = src; src = dst; dst = tmp;
    }

    // write output tile (result is in src after final swap)
    for (int c = tid; c < 1024; c += 256) {
        int li = 7 + (c >> 5), lj = 7 + (c & 31);
        Vfin[(gy0 + li) * WW + gx0 + lj] = src[li * TS + lj];
    }
}

// ---------------- bilinear grid sample (align_corners, border clamp) ----------------
__global__ void sample_kernel(const float* __restrict__ x,
                              const float* __restrict__ V,
                              float* __restrict__ out) {
    int idx = blockIdx.x * 256 + threadIdx.x;
    float2 g2 = ((const float2*)x)[idx];
    float ix = (g2.x + 1.0f) * 0.5f * 511.0f;
    float iy = (g2.y + 1.0f) * 0.5f * 511.0f;
    ix = fminf(fmaxf(ix, 0.0f), 511.0f);
    iy = fminf(fmaxf(iy, 0.0f), 511.0f);
    int x0 = (int)floorf(ix), y0 = (int)floorf(iy);
    int x1 = min(x0 + 1, 511), y1 = min(y0 + 1, 511);
    float wx = ix - (float)x0, wy = iy - (float)y0;
    float v00 = V[y0 * 512 + x0], v01 = V[y0 * 512 + x1];
    float v10 = V[y1 * 512 + x0], v11 = V[y1 * 512 + x1];
    float v = v00 * (1.0f - wx) * (1.0f - wy) + v01 * wx * (1.0f - wy)
            + v10 * (1.0f - wx) * wy          + v11 * wx * wy;
    out[idx] = v;   // output 0
}

extern "C" void kernel_launch(void* const* d_in, const int* in_sizes, int n_in,
                              void* d_out, int out_size, void* d_ws, size_t ws_size,
                              hipStream_t stream) {
    const float* x    = (const float*)d_in[0];
    const int*   bt   = (const int*)d_in[1];
    const float* bc   = (const float*)d_in[2];
    const float* benc = (const float*)d_in[3];
    const float* Wh   = (const float*)d_in[4];
    const float* wout = (const float*)d_in[5];

    char* ws = (char*)d_ws;
    ushort_t* WT   = (ushort_t*)(ws + 4096);
    float*    C_ws = (float*)(ws + 262144);
    float*    Vfin = (float*)(ws + 262144 + 3 * (1 << 20));
    float*    outp = (float*)d_out;

    prep_kernel<<<32, 256, 0, stream>>>(Wh, (uint4*)WT);
    mlp_kernel<<<2048, 256, 0, stream>>>(x, WT, benc, wout, C_ws, outp);
    fused_solve_kernel<<<256, 256, 0, stream>>>(bt, bc, C_ws, Vfin);
    sample_kernel<<<1024, 256, 0, stream>>>(x, Vfin, outp);
}